// Round 21
// baseline (177.275 us; speedup 1.0000x reference)
//
#include <hip/hip_runtime.h>

// LinearAutoDecoder R21: R20 structure + depth-3 slab pipeline with counted
// s_waitcnt vmcnt(N) (T4). R20's limiter: depth-2 syncthreads waits for the
// whole slab t+1 delivery each tile (issued same iteration; compute covers
// ~1/3 of it) -> HBM ~70% busy. Depth-3: stages t,t+1,t+2 in flight; per
// iteration wait vmcnt(10) (= oldest 5 loads, slab t, done -- in-order
// semantics m135), raw s_barrier (no vm drain), compute(t), barrier,
// stage(t+3). Two tiles of delivery slack -> HBM saturated.
// Staging is exactly 5 unconditional loads/thread (addresses clamped, writes
// land in a 64-dword LDS pad) so static vmcnt counts are uniform.

constexpr int POS = 63, LAT = 256, DIM = 319, NCH = 192;
constexpr int ROWS = 16;                     // rows per tile
constexpr int PW_DW = NCH * 160;             // 30720 dwords (320 bf16/ch)
constexpr size_t PW_BYTES = (size_t)PW_DW * 4;
constexpr int TILE_DW = ROWS * DIM;          // 5104 dwords
constexpr int TILE_F4 = TILE_DW / 4;         // 1276 float4 per slab
constexpr int BUF_DW = 5120;                 // padded buffer (pad absorbs clamp)
constexpr int GRID = 512;                    // 2 blocks/CU

typedef __attribute__((ext_vector_type(8))) short short8;
typedef __attribute__((ext_vector_type(4))) float f32x4;

__device__ __forceinline__ unsigned f2bf(float f) {
    unsigned u = __float_as_uint(f);
    return (u + 0x7fffu + ((u >> 16) & 1u)) >> 16;
}

// pw[ch*160 + d] = bf16(w[ch][2d]) | bf16(w[ch][2d+1])<<16 ; k=319 -> 0
__global__ __launch_bounds__(256) void pack_weights(
    const float* __restrict__ Wp, const float* __restrict__ Wf,
    unsigned* __restrict__ pw)
{
    const int idx = blockIdx.x * 256 + threadIdx.x;
    if (idx >= PW_DW) return;
    const int ch = idx / 160, d = idx - ch * 160;
    auto wat = [&](int k) -> float {
        if (k < POS) return Wp[ch * POS + k];
        if (k < DIM) return Wf[ch * LAT + (k - POS)];
        return 0.f;
    };
    pw[idx] = f2bf(wat(2 * d)) | (f2bf(wat(2 * d + 1)) << 16);
}

__global__ __launch_bounds__(256, 2) void lad_mfma4(
    const float4* __restrict__ X4, const int* __restrict__ cid,
    const unsigned* __restrict__ pw, float* __restrict__ out,
    int ntiles, int tpb)
{
    __shared__ float xb[3][BUF_DW];    // 61,440 B -> 2 blocks/CU

    const int thr = threadIdx.x;
    const int l   = thr & 63;
    const int wid = thr >> 6;
    const int n0  = wid * 48;          // wave's channel base
    const int cl  = l & 15;            // row(A) / col(B,C)
    const int q   = l >> 4;            // k-quad

    // B fragments: 48 channels x K=320 in VGPRs (R17-proven load).
    short8 Bf[3][10];
#pragma unroll
    for (int nt = 0; nt < 3; ++nt)
#pragma unroll
        for (int kk = 0; kk < 10; ++kk)
            Bf[nt][kk] = *reinterpret_cast<const short8*>(
                pw + (size_t)(n0 + nt * 16 + cl) * 160 + kk * 16 + q * 4);

    const int t0 = blockIdx.x * tpb;
    const int tend = min(t0 + tpb, ntiles);
    if (t0 >= tend) return;

    // Stage: EXACTLY 5 global_load_lds per thread (uniform vmcnt accounting).
    // Slots >= TILE_F4 clamp the global address and land in the LDS pad.
    auto stage = [&](int tile, int p) {
        const float4* src = X4 + (size_t)tile * TILE_F4;
#pragma unroll
        for (int j = 0; j < 5; ++j) {
            const int slot = j * 256 + thr;              // 0..1279 < 1280
            const int gs   = slot < TILE_F4 ? slot : TILE_F4 - 1;
            __builtin_amdgcn_global_load_lds(
                (const __attribute__((address_space(1))) unsigned int*)(src + gs),
                (__attribute__((address_space(3))) unsigned int*)&xb[p][slot * 4],
                16, 0, 0);
        }
    };

    // Prologue: 3 slabs in flight (15 loads/thread outstanding).
    stage(t0,     0);
    stage(min(t0 + 1, ntiles - 1), 1);
    stage(min(t0 + 2, ntiles - 1), 2);

    int pi = 0;                        // buffer index of tile t
    for (int t = t0; t < tend; ++t) {
        // Oldest 5 loads (slab t) complete; slabs t+1, t+2 keep flying.
        asm volatile("s_waitcnt vmcnt(10)" ::: "memory");
        __builtin_amdgcn_sched_barrier(0);
        __builtin_amdgcn_s_barrier();       // all waves: slab t visible
        __builtin_amdgcn_sched_barrier(0);

        const float* cur = xb[pi];

        // cid for this lane's 4 output rows (compiler-counted vm wait; the
        // 10 outstanding stage loads remain in flight).
        int c3v[4];
#pragma unroll
        for (int j = 0; j < 4; ++j)
            c3v[j] = 3 * cid[(size_t)t * ROWS + q * 4 + j];

        f32x4 acc[3];
#pragma unroll
        for (int nt = 0; nt < 3; ++nt)
            acc[nt] = (f32x4)0.0f;

        // MFMA over K=320: A-frag fp32 from LDS, cvt_pk to bf16 in-register.
#pragma unroll
        for (int kk = 0; kk < 10; ++kk) {
            const float* fp = &cur[cl * DIM + kk * 32 + q * 8];
            union { unsigned u[4]; short8 s; } cv;
#pragma unroll
            for (int h = 0; h < 4; ++h) {
                asm("v_cvt_pk_bf16_f32 %0, %1, %2"
                    : "=v"(cv.u[h]) : "v"(fp[2 * h]), "v"(fp[2 * h + 1]));
            }
#pragma unroll
            for (int nt = 0; nt < 3; ++nt)
                acc[nt] = __builtin_amdgcn_mfma_f32_16x16x32_bf16(
                    cv.s, Bf[nt][kk], acc[nt], 0, 0, 0);
        }

        // Sparse direct output (mapping R17/R19/R20-proven).
#pragma unroll
        for (int j = 0; j < 4; ++j) {
            const int grow = t * ROWS + q * 4 + j;
            const int c3 = c3v[j];
#pragma unroll
            for (int nt = 0; nt < 3; ++nt) {
                const int col = n0 + nt * 16 + cl;
                const unsigned d = (unsigned)(col - c3);
                if (d < 3u)
                    out[(size_t)grow * 3 + d] = acc[nt][j];
            }
        }

        __builtin_amdgcn_s_barrier();       // all waves done reading xb[pi]
        __builtin_amdgcn_sched_barrier(0);

        // Refill the buffer just freed with slab t+3 (clamped; uniform count).
        stage(min(t + 3, ntiles - 1), pi);

        pi = (pi == 2) ? 0 : pi + 1;
    }

    asm volatile("s_waitcnt vmcnt(0)" ::: "memory");   // drain before endpgm
}

// ---------- fallback (R2-style, fp32 weights, no workspace) ----------
template <int CTRL>
__device__ __forceinline__ float dpp_add_step(float x) {
    int s = __builtin_amdgcn_update_dpp(0, __float_as_int(x), CTRL,
                                        0xF, 0xF, true);
    return x + __int_as_float(s);
}
__device__ __forceinline__ float wave_reduce_sum(float x) {
    x = dpp_add_step<0x111>(x);
    x = dpp_add_step<0x112>(x);
    x = dpp_add_step<0x114>(x);
    x = dpp_add_step<0x118>(x);
    x = dpp_add_step<0x142>(x);
    x = dpp_add_step<0x143>(x);
    return x;   // lane 63
}

__global__ __launch_bounds__(256) void lad_fallback(
    const float* __restrict__ X, const int* __restrict__ cid,
    const float* __restrict__ Wp, const float* __restrict__ Wf,
    float* __restrict__ out, int n)
{
    const int lane = threadIdx.x & 63;
    const int wave = (int)((blockIdx.x * blockDim.x + threadIdx.x) >> 6);
    if (wave >= n) return;
    const size_t row = (size_t)wave;
    const float* xrow = X + row * (size_t)DIM;
    const float* xf   = xrow + POS;
    const int c3 = cid[row] * 3;
    const float* wp0 = Wp + (size_t)c3 * POS;
    const float* wf0 = Wf + (size_t)c3 * LAT;
    float a0 = 0.f, a1 = 0.f, a2 = 0.f;
#pragma unroll
    for (int i = 0; i < 4; ++i) {
        const int k = lane + 64 * i;
        const float x = xf[k];
        a0 = fmaf(x, wf0[k], a0);
        a1 = fmaf(x, wf0[k + LAT], a1);
        a2 = fmaf(x, wf0[k + 2 * LAT], a2);
    }
    if (lane < POS) {
        const float x = xrow[lane];
        a0 = fmaf(x, wp0[lane], a0);
        a1 = fmaf(x, wp0[lane + POS], a1);
        a2 = fmaf(x, wp0[lane + 2 * POS], a2);
    }
    a0 = wave_reduce_sum(a0);
    a1 = wave_reduce_sum(a1);
    a2 = wave_reduce_sum(a2);
    if (lane == 63) {
        float* o = out + row * 3;
        o[0] = a0; o[1] = a1; o[2] = a2;
    }
}

extern "C" void kernel_launch(void* const* d_in, const int* in_sizes, int n_in,
                              void* d_out, int out_size, void* d_ws, size_t ws_size,
                              hipStream_t stream) {
    const float* X   = (const float*)d_in[0];
    const int*   cid = (const int*)d_in[1];
    const float* Wp  = (const float*)d_in[2];
    const float* Wf  = (const float*)d_in[3];
    float* out = (float*)d_out;
    const int n = in_sizes[1];

    if (ws_size >= PW_BYTES && n > 0 && (n % ROWS) == 0 && n / ROWS >= 4) {
        unsigned* pw = (unsigned*)d_ws;
        pack_weights<<<(PW_DW + 255) / 256, 256, 0, stream>>>(Wp, Wf, pw);
        const int ntiles = n / ROWS;                       // 32768
        const int tpb = (ntiles + GRID - 1) / GRID;        // 64
        lad_mfma4<<<GRID, 256, 0, stream>>>((const float4*)X, cid, pw, out,
                                            ntiles, tpb);
    } else {
        const int blocks = (n + 3) / 4;
        lad_fallback<<<blocks, 256, 0, stream>>>(X, cid, Wp, Wf, out, n);
    }
}

// Round 22
// 147.150 us; speedup vs baseline: 1.2047x; 1.2047x over previous
//
#include <hip/hip_runtime.h>

// LinearAutoDecoder FINAL (= R20, best measured: 146.5us, absmax 0.03125).
// Structure: dense MFMA per 16-row tile; X streamed as contiguous float4
// slabs DIRECTLY into LDS via global_load_lds (probe-proven 6.55 TB/s
// pattern); all 192 channel weights bf16-packed in VGPRs as MFMA B-fragments
// (loaded once per block); A-fragments assembled from LDS fp32 with fused
// v_cvt_pk_bf16_f32; per-row 3-channel gather done as sparse direct stores
// from the accumulator (no cbuf, no cross-lane reduce anywhere).
// Double-buffered slabs + 3 anti-phased blocks/CU (launch_bounds(256,3)).
// Session ladder: 216.9 (R1) -> 173 (binning) -> 165.7 (coalesced MFMA) ->
// 153.9 (no reg-staging) -> 146.5 (3 blocks/CU). Depth-3 counted-vmcnt and
// 2-block variants regressed (R21: 177; R19: 153.9) -- occupancy > depth.

constexpr int POS = 63, LAT = 256, DIM = 319, NCH = 192;
constexpr int ROWS = 16;                     // rows per tile
constexpr int PW_DW = NCH * 160;             // 30720 dwords (320 bf16/ch)
constexpr size_t PW_BYTES = (size_t)PW_DW * 4;
constexpr int TILE_DW = ROWS * DIM;          // 5104 dwords
constexpr int TILE_F4 = TILE_DW / 4;         // 1276 float4 per slab
constexpr int GRID = 768;                    // 3 blocks/CU, all resident

typedef __attribute__((ext_vector_type(8))) short short8;
typedef __attribute__((ext_vector_type(4))) float f32x4;

__device__ __forceinline__ unsigned f2bf(float f) {
    unsigned u = __float_as_uint(f);
    return (u + 0x7fffu + ((u >> 16) & 1u)) >> 16;
}

// pw[ch*160 + d] = bf16(w[ch][2d]) | bf16(w[ch][2d+1])<<16 ; k=319 -> 0
__global__ __launch_bounds__(256) void pack_weights(
    const float* __restrict__ Wp, const float* __restrict__ Wf,
    unsigned* __restrict__ pw)
{
    const int idx = blockIdx.x * 256 + threadIdx.x;
    if (idx >= PW_DW) return;
    const int ch = idx / 160, d = idx - ch * 160;
    auto wat = [&](int k) -> float {
        if (k < POS) return Wp[ch * POS + k];
        if (k < DIM) return Wf[ch * LAT + (k - POS)];
        return 0.f;
    };
    pw[idx] = f2bf(wat(2 * d)) | (f2bf(wat(2 * d + 1)) << 16);
}

__global__ __launch_bounds__(256, 3) void lad_mfma3(
    const float4* __restrict__ X4, const int* __restrict__ cid,
    const unsigned* __restrict__ pw, float* __restrict__ out,
    int ntiles, int tpb)
{
    __shared__ float xb[2][TILE_DW];   // 40,832 B -> 3 blocks/CU

    const int thr = threadIdx.x;
    const int l   = thr & 63;
    const int wid = thr >> 6;
    const int n0  = wid * 48;          // wave's channel base
    const int cl  = l & 15;            // row(A) / col(B,C)
    const int q   = l >> 4;            // k-quad

    // B fragments: 48 channels x K=320 in VGPRs.
    short8 Bf[3][10];
#pragma unroll
    for (int nt = 0; nt < 3; ++nt)
#pragma unroll
        for (int kk = 0; kk < 10; ++kk)
            Bf[nt][kk] = *reinterpret_cast<const short8*>(
                pw + (size_t)(n0 + nt * 16 + cl) * 160 + kk * 16 + q * 4);

    const int t0 = blockIdx.x * tpb;
    const int tend = min(t0 + tpb, ntiles);
    if (t0 >= tend) return;

    // Direct-to-LDS slab stage: lane-contiguous dwordx4 (probe pattern).
    auto stage = [&](int tile, int p) {
        const float4* src = X4 + (size_t)tile * TILE_F4;
#pragma unroll
        for (int j = 0; j < 5; ++j) {
            const int slot = j * 256 + thr;
            if (slot < TILE_F4)
                __builtin_amdgcn_global_load_lds(
                    (const __attribute__((address_space(1))) unsigned int*)(src + slot),
                    (__attribute__((address_space(3))) unsigned int*)&xb[p][slot * 4],
                    16, 0, 0);
        }
    };

    stage(t0, 0);
    __syncthreads();                   // prologue drain

    int p = 0;
    for (int t = t0; t < tend; ++t) {
        // Fire next slab into the other buffer: delivers under MFMA below.
        if (t + 1 < tend) stage(t + 1, p ^ 1);

        // cid for this lane's 4 output rows (L1-hot, overlaps MFMA).
        int c3v[4];
#pragma unroll
        for (int j = 0; j < 4; ++j)
            c3v[j] = 3 * cid[(size_t)t * ROWS + q * 4 + j];

        f32x4 acc[3];
#pragma unroll
        for (int nt = 0; nt < 3; ++nt)
            acc[nt] = (f32x4)0.0f;

        // MFMA over K=320: A-frag reads fp32 from LDS, cvt_pk to bf16 in-reg.
#pragma unroll
        for (int kk = 0; kk < 10; ++kk) {
            const float* fp = &xb[p][cl * DIM + kk * 32 + q * 8];
            union { unsigned u[4]; short8 s; } cv;
#pragma unroll
            for (int h = 0; h < 4; ++h) {
                asm("v_cvt_pk_bf16_f32 %0, %1, %2"
                    : "=v"(cv.u[h]) : "v"(fp[2 * h]), "v"(fp[2 * h + 1]));
            }
#pragma unroll
            for (int nt = 0; nt < 3; ++nt)
                acc[nt] = __builtin_amdgcn_mfma_f32_16x16x32_bf16(
                    cv.s, Bf[nt][kk], acc[nt], 0, 0, 0);
        }

        // Sparse direct output: lane stores acc elements whose col hits the
        // row's 3 selected channels (C layout: col=lane&15, row=(lane>>4)*4+j).
#pragma unroll
        for (int j = 0; j < 4; ++j) {
            const int grow = t * ROWS + q * 4 + j;
            const int c3 = c3v[j];
#pragma unroll
            for (int nt = 0; nt < 3; ++nt) {
                const int col = n0 + nt * 16 + cl;
                const unsigned d = (unsigned)(col - c3);
                if (d < 3u)
                    out[(size_t)grow * 3 + d] = acc[nt][j];
            }
        }

        __syncthreads();   // drains slab(t+1) + stores; buffers swap safely
        p ^= 1;
    }
}

// ---------- fallback (R2-style, fp32 weights, no workspace) ----------
template <int CTRL>
__device__ __forceinline__ float dpp_add_step(float x) {
    int s = __builtin_amdgcn_update_dpp(0, __float_as_int(x), CTRL,
                                        0xF, 0xF, true);
    return x + __int_as_float(s);
}
__device__ __forceinline__ float wave_reduce_sum(float x) {
    x = dpp_add_step<0x111>(x);
    x = dpp_add_step<0x112>(x);
    x = dpp_add_step<0x114>(x);
    x = dpp_add_step<0x118>(x);
    x = dpp_add_step<0x142>(x);
    x = dpp_add_step<0x143>(x);
    return x;   // lane 63
}

__global__ __launch_bounds__(256) void lad_fallback(
    const float* __restrict__ X, const int* __restrict__ cid,
    const float* __restrict__ Wp, const float* __restrict__ Wf,
    float* __restrict__ out, int n)
{
    const int lane = threadIdx.x & 63;
    const int wave = (int)((blockIdx.x * blockDim.x + threadIdx.x) >> 6);
    if (wave >= n) return;
    const size_t row = (size_t)wave;
    const float* xrow = X + row * (size_t)DIM;
    const float* xf   = xrow + POS;
    const int c3 = cid[row] * 3;
    const float* wp0 = Wp + (size_t)c3 * POS;
    const float* wf0 = Wf + (size_t)c3 * LAT;
    float a0 = 0.f, a1 = 0.f, a2 = 0.f;
#pragma unroll
    for (int i = 0; i < 4; ++i) {
        const int k = lane + 64 * i;
        const float x = xf[k];
        a0 = fmaf(x, wf0[k], a0);
        a1 = fmaf(x, wf0[k + LAT], a1);
        a2 = fmaf(x, wf0[k + 2 * LAT], a2);
    }
    if (lane < POS) {
        const float x = xrow[lane];
        a0 = fmaf(x, wp0[lane], a0);
        a1 = fmaf(x, wp0[lane + POS], a1);
        a2 = fmaf(x, wp0[lane + 2 * POS], a2);
    }
    a0 = wave_reduce_sum(a0);
    a1 = wave_reduce_sum(a1);
    a2 = wave_reduce_sum(a2);
    if (lane == 63) {
        float* o = out + row * 3;
        o[0] = a0; o[1] = a1; o[2] = a2;
    }
}

extern "C" void kernel_launch(void* const* d_in, const int* in_sizes, int n_in,
                              void* d_out, int out_size, void* d_ws, size_t ws_size,
                              hipStream_t stream) {
    const float* X   = (const float*)d_in[0];
    const int*   cid = (const int*)d_in[1];
    const float* Wp  = (const float*)d_in[2];
    const float* Wf  = (const float*)d_in[3];
    float* out = (float*)d_out;
    const int n = in_sizes[1];

    if (ws_size >= PW_BYTES && n > 0 && (n % ROWS) == 0) {
        unsigned* pw = (unsigned*)d_ws;
        pack_weights<<<(PW_DW + 255) / 256, 256, 0, stream>>>(Wp, Wf, pw);
        const int ntiles = n / ROWS;                       // 32768
        const int tpb = (ntiles + GRID - 1) / GRID;        // 43
        lad_mfma3<<<GRID, 256, 0, stream>>>((const float4*)X, cid, pw, out,
                                            ntiles, tpb);
    } else {
        const int blocks = (n + 3) / 4;
        lad_fallback<<<blocks, 256, 0, stream>>>(X, cid, Wp, Wf, out, n);
    }
}